// Round 4
// baseline (3493.683 us; speedup 1.0000x reference)
//
#include <hip/hip_runtime.h>

#define NELEM  200000
#define NREACT 100000
#define EDIM   200
#define RDIM   128
#define F0     328
#define F0PAD  352      // K padded to multiple of 32 for layer 0
#define NH     3
#define MT     64       // rows per block tile
#define NT     512      // 8 waves: 6 waves/SIMD at 3 blocks/CU (latency hiding)
#define SA     360      // LDS row stride (elems); 720 B rows; A-reads/epilogue bank-minimal

typedef _Float16 f16x8 __attribute__((ext_vector_type(8)));
typedef _Float16 f16x4 __attribute__((ext_vector_type(4)));
typedef float    f32x4 __attribute__((ext_vector_type(4)));

// ---------------- fused weight convert + transpose prepass ----------------
// src fp32 [H][K][N] -> dst fp16 [H][N][Kpad], zero-padded for k >= K.
// LDS-transposed: coalesced global reads (consecutive n) and coalesced
// fp16 writes (consecutive k). Tile = 32 k x 64 n.
struct WSeg { const float* src; _Float16* dst; int K, N, Kpad, nb; };
struct WTab { WSeg s[10]; };

__global__ void wconv_all(WTab t)
{
    __shared__ float sT[64 * 33];   // [n_local][k_local], stride 33 (conflict-free)
    int b = blockIdx.x;
    for (int i = 0; i < 10; ++i) {
        if (b < t.s[i].nb) {
            const WSeg g = t.s[i];
            const int ntn = 3 * g.N / 64;          // col tiles over H*N
            const int tn = b % ntn, tk = b / ntn;
            const int col = tn * 64;               // global col in [0, 3*N)
            const int h = col / g.N, n0 = col - h * g.N;
            const int k0 = tk * 32;
            const int tid = threadIdx.x;

            // read 32k x 64n tile, coalesced in n
            const int nl = tid & 63;
            for (int kk = tid >> 6; kk < 32; kk += 4) {
                const int k = k0 + kk;
                float v = (k < g.K) ? g.src[((size_t)h * g.K + k) * g.N + n0 + nl] : 0.f;
                sT[nl * 33 + kk] = v;
            }
            __syncthreads();

            // write transposed, coalesced in k
            const int kl = tid & 31;
            for (int nn = tid >> 5; nn < 64; nn += 8)
                g.dst[(size_t)(col + nn) * g.Kpad + k0 + kl] = (_Float16)sT[nn * 33 + kl];
            return;
        }
        b -= t.s[i].nb;
    }
}

// ---------------- sched_group_barrier pinning helpers (T19) ----------------
// Masks: MFMA=0x008, VMEM_READ=0x020, DS_READ=0x100.
// Pin one pipeline step: 4*TN MFMAs interleaved with TN global b-loads
// and 4 LDS a-loads (refill for step kt+2). Forces the machine scheduler
// to EMIT prefetch loads between MFMA clusters (R3: +33%, MfmaUtil 14->21).
template<int TN>
__device__ __forceinline__ void pin_step_refill()
{
    if constexpr (TN == 2) {
#pragma unroll
        for (int g = 0; g < 2; ++g) {
            __builtin_amdgcn_sched_group_barrier(0x008, 2, 0);
            __builtin_amdgcn_sched_group_barrier(0x020, 1, 0);
            __builtin_amdgcn_sched_group_barrier(0x008, 2, 0);
            __builtin_amdgcn_sched_group_barrier(0x100, 2, 0);
        }
    } else {   // TN == 1
        __builtin_amdgcn_sched_group_barrier(0x008, 2, 0);
        __builtin_amdgcn_sched_group_barrier(0x020, 1, 0);
        __builtin_amdgcn_sched_group_barrier(0x008, 2, 0);
        __builtin_amdgcn_sched_group_barrier(0x100, 4, 0);
    }
}

template<int N>
__device__ __forceinline__ void pin_step_mfma_only()
{
    __builtin_amdgcn_sched_group_barrier(0x008, N, 0);
}

// ---------------- one GEMM pass, depth-2 modulo pipeline, SGB-pinned ----------------
// Output layout is SWAPPED mfma(b, a): lane holds 4 consecutive COLS (q*4+i) of one row (r).
template<int TN, int KSTEPS, int KPAD>
__device__ __forceinline__ void gemm_pass(
    const _Float16* __restrict__ buf,
    const _Float16* __restrict__ w,
    f32x4 (&acc)[4][TN], int n0, int r, int q)
{
    const _Float16* aBase = buf + r * SA + q * 8;
    const _Float16* wBase = w + ((size_t)n0 + r) * KPAD + q * 8;

    f16x8 a0[4], a1[4], b0[TN], b1[TN];
#pragma unroll
    for (int nt = 0; nt < TN; ++nt) b0[nt] = *(const f16x8*)(wBase + (size_t)nt * 16 * KPAD);
#pragma unroll
    for (int mt = 0; mt < 4; ++mt) a0[mt] = *(const f16x8*)(aBase + mt * 16 * SA);
#pragma unroll
    for (int nt = 0; nt < TN; ++nt) b1[nt] = *(const f16x8*)(wBase + (size_t)nt * 16 * KPAD + 32);
#pragma unroll
    for (int mt = 0; mt < 4; ++mt) a1[mt] = *(const f16x8*)(aBase + mt * 16 * SA + 32);

#pragma unroll
    for (int kt = 0; kt < KSTEPS; kt += 2) {
        // even step: consume set0, refill set0 for kt+2
#pragma unroll
        for (int nt = 0; nt < TN; ++nt)
#pragma unroll
            for (int mt = 0; mt < 4; ++mt)
                acc[mt][nt] = __builtin_amdgcn_mfma_f32_16x16x32_f16(b0[nt], a0[mt], acc[mt][nt], 0, 0, 0);
        if (kt + 2 < KSTEPS) {
#pragma unroll
            for (int nt = 0; nt < TN; ++nt)
                b0[nt] = *(const f16x8*)(wBase + (size_t)nt * 16 * KPAD + (kt + 2) * 32);
#pragma unroll
            for (int mt = 0; mt < 4; ++mt)
                a0[mt] = *(const f16x8*)(aBase + mt * 16 * SA + (kt + 2) * 32);
            pin_step_refill<TN>();
        } else {
            pin_step_mfma_only<4 * TN>();
        }
        // odd step: consume set1, refill set1 for kt+3
        if (kt + 1 < KSTEPS) {
#pragma unroll
            for (int nt = 0; nt < TN; ++nt)
#pragma unroll
                for (int mt = 0; mt < 4; ++mt)
                    acc[mt][nt] = __builtin_amdgcn_mfma_f32_16x16x32_f16(b1[nt], a1[mt], acc[mt][nt], 0, 0, 0);
            if (kt + 3 < KSTEPS) {
#pragma unroll
                for (int nt = 0; nt < TN; ++nt)
                    b1[nt] = *(const f16x8*)(wBase + (size_t)nt * 16 * KPAD + (kt + 3) * 32);
#pragma unroll
                for (int mt = 0; mt < 4; ++mt)
                    a1[mt] = *(const f16x8*)(aBase + mt * 16 * SA + (kt + 3) * 32);
                pin_step_refill<TN>();
            } else {
                pin_step_mfma_only<4 * TN>();
            }
        }
    }
}

// ---------------- identity-residual layer, in-place ----------------
// `active`: wave participates in compute; ALL waves hit both barriers.
template<int TN, int KSTEPS, int KPAD>
__device__ __forceinline__ void layer_id(
    bool active, _Float16* __restrict__ buf,
    const _Float16* __restrict__ wFc,
    const float* __restrict__ bias, int n0, int lane)
{
    const int r = lane & 15, q = lane >> 4;
    f32x4 acc[4][TN];
    if (active) {
#pragma unroll
        for (int mt = 0; mt < 4; ++mt)
#pragma unroll
            for (int nt = 0; nt < TN; ++nt) acc[mt][nt] = (f32x4){0.f, 0.f, 0.f, 0.f};
        gemm_pass<TN, KSTEPS, KPAD>(buf, wFc, acc, n0, r, q);
    }

    __syncthreads();   // all waves' reads of buf complete before overwrite

    if (active) {
#pragma unroll
        for (int nt = 0; nt < TN; ++nt) {
            const int colb = n0 + nt * 16 + q * 4;
            const f32x4 bv = *(const f32x4*)(bias + colb);
#pragma unroll
            for (int mt = 0; mt < 4; ++mt) {
                _Float16* p = buf + (mt * 16 + r) * SA + colb;
                f16x4 o = *(const f16x4*)p;       // residual (same thread read-then-write)
                f16x4 z;
#pragma unroll
                for (int i = 0; i < 4; ++i)
                    z[i] = (_Float16)(fmaxf(acc[mt][nt][i] + bv[i], 0.f) + (float)o[i]);
                *(f16x4*)p = z;
            }
        }
    }
    __syncthreads();   // outputs visible before next layer reads
}

// ---------------- projection-residual layer, in-place ----------------
// pass1: acc = fea*Wfc; relu(acc+bias) in f32; pass2: acc += fea*Wres (MFMA C-in is the add)
template<int TN, int KSTEPS, int KPAD>
__device__ __forceinline__ void layer_proj(
    bool active, _Float16* __restrict__ buf,
    const _Float16* __restrict__ wFc, const _Float16* __restrict__ wRes,
    const float* __restrict__ bias, int n0, int lane)
{
    const int r = lane & 15, q = lane >> 4;
    f32x4 acc[4][TN];
    if (active) {
#pragma unroll
        for (int mt = 0; mt < 4; ++mt)
#pragma unroll
            for (int nt = 0; nt < TN; ++nt) acc[mt][nt] = (f32x4){0.f, 0.f, 0.f, 0.f};

        gemm_pass<TN, KSTEPS, KPAD>(buf, wFc, acc, n0, r, q);

#pragma unroll
        for (int nt = 0; nt < TN; ++nt) {
            const f32x4 bv = *(const f32x4*)(bias + n0 + nt * 16 + q * 4);
#pragma unroll
            for (int mt = 0; mt < 4; ++mt)
#pragma unroll
                for (int i = 0; i < 4; ++i)
                    acc[mt][nt][i] = fmaxf(acc[mt][nt][i] + bv[i], 0.f);
        }

        gemm_pass<TN, KSTEPS, KPAD>(buf, wRes, acc, n0, r, q);   // residual accumulates on top
    }

    __syncthreads();   // all waves' reads of buf complete before overwrite

    if (active) {
#pragma unroll
        for (int nt = 0; nt < TN; ++nt) {
            const int colb = n0 + nt * 16 + q * 4;
#pragma unroll
            for (int mt = 0; mt < 4; ++mt) {
                f16x4 z;
#pragma unroll
                for (int i = 0; i < 4; ++i) z[i] = (_Float16)acc[mt][nt][i];
                *(f16x4*)(buf + (mt * 16 + r) * SA + colb) = z;
            }
        }
    }
    __syncthreads();
}

// ---------------- fused MLP kernel ----------------
__global__ __launch_bounds__(NT, 6)
void mlp_mfma(const float* __restrict__ elem, const int* __restrict__ ridx,
              const float* __restrict__ embed,
              const _Float16* __restrict__ wb,
              const float* __restrict__ fcb0, const float* __restrict__ fcb1,
              const float* __restrict__ fcb2, const float* __restrict__ fcb3,
              const float* __restrict__ fcb4, const float* __restrict__ fcb5,
              const float* __restrict__ fcb6,
              const float* __restrict__ outW, const float* __restrict__ outb,
              float* __restrict__ gate, unsigned int* __restrict__ segmax)
{
    __shared__ __align__(16) _Float16 sX[MT * SA];   // 46080 B, in-place all layers
    __shared__ int sidx[MT];

    const int tid = threadIdx.x, lane = tid & 63, wave = tid >> 6;
    const int head = blockIdx.y;                 // head-major dispatch: one head's weights stay L2-resident
    const int row0 = blockIdx.x * MT;

    if (tid < MT) sidx[tid] = ridx[row0 + tid];
    __syncthreads();

    // stage concat(elem, embed[idx]) -> fp16 in sX, float4 loads + 8B LDS writes
    for (int rr = wave; rr < MT; rr += 8) {
        const float* es = elem + (size_t)(row0 + rr) * EDIM;
        const float* ms = embed + (size_t)sidx[rr] * RDIM;
        for (int c = lane; c < F0PAD / 4; c += 64) {          // 88 chunks of 4 floats
            f32x4 v;
            if (c < EDIM / 4)            v = *(const f32x4*)(es + 4 * c);
            else if (c < F0 / 4)         v = *(const f32x4*)(ms + 4 * c - EDIM);
            else                         v = (f32x4){0.f, 0.f, 0.f, 0.f};
            f16x4 hv;
#pragma unroll
            for (int i = 0; i < 4; ++i) hv[i] = (_Float16)v[i];
            *(f16x4*)(sX + rr * SA + 4 * c) = hv;
        }
    }
    __syncthreads();

    const size_t h = head;
    const int n32 = wave * 32, n16 = wave * 16;

    // weight blob offsets (fp16 elems)
    const _Float16* wt_fc0  = wb;
    const _Float16* wt_res0 = wb + 270336;
    const _Float16* wt_fc1  = wb + 540672;
    const _Float16* wt_fc2  = wb + 737280;
    const _Float16* wt_fc3  = wb + 933888;
    const _Float16* wt_fc4  = wb + 1130496;
    const _Float16* wt_res4 = wb + 1228800;
    const _Float16* wt_fc5  = wb + 1327104;
    const _Float16* wt_fc6  = wb + 1376256;
    const _Float16* wt_res6 = wb + 1400832;

    // 8 waves: N=256 layers -> TN=2 (32 cols/wave); N=128 -> TN=1 (16 cols/wave);
    // N=64 -> waves 0-3 only (TN=1), waves 4-7 park at the barriers.
    layer_proj<2, 11, 352>(true, sX, wt_fc0 + h * 90112, wt_res0 + h * 90112, fcb0 + h * 256, n32, lane);
    layer_id  <2, 8, 256>(true, sX, wt_fc1 + h * 65536, fcb1 + h * 256, n32, lane);
    layer_id  <2, 8, 256>(true, sX, wt_fc2 + h * 65536, fcb2 + h * 256, n32, lane);
    layer_id  <2, 8, 256>(true, sX, wt_fc3 + h * 65536, fcb3 + h * 256, n32, lane);
    layer_proj<1, 8, 256>(true, sX, wt_fc4 + h * 32768, wt_res4 + h * 32768, fcb4 + h * 128, n16, lane);
    layer_id  <1, 4, 128>(true, sX, wt_fc5 + h * 16384, fcb5 + h * 128, n16, lane);
    layer_proj<1, 4, 128>(wave < 4, sX, wt_fc6 + h * 8192, wt_res6 + h * 8192, fcb6 + h * 64, n16, lane);

    // gate = h64 . outW + outb ; one thread per row, vectorized LDS reads
    if (tid < MT) {
        const _Float16* hv = sX + tid * SA;
        const float* wv = outW + h * 64;
        float g = outb[head];
#pragma unroll
        for (int j = 0; j < 8; ++j) {
            f16x8 hx = *(const f16x8*)(hv + j * 8);
#pragma unroll
            for (int i = 0; i < 8; ++i) g = fmaf((float)hx[i], wv[j * 8 + i], g);
        }
        gate[head * NELEM + row0 + tid] = g;
        unsigned int bits = __float_as_uint(g);
        unsigned int enc  = (bits & 0x80000000u) ? ~bits : (bits | 0x80000000u);
        atomicMax(&segmax[head * NREACT + sidx[tid]], enc);
    }
}

// ---------------- softmax phases ----------------
__global__ void phase2_kernel(float* __restrict__ gate, const int* __restrict__ ridx,
                              const unsigned int* __restrict__ segmax,
                              float* __restrict__ segsum)
{
    int i = blockIdx.x * blockDim.x + threadIdx.x;
    if (i >= NH * NELEM) return;
    int h = i / NELEM;
    int n = i - h * NELEM;
    int j = ridx[n];
    unsigned int enc  = segmax[h * NREACT + j];
    unsigned int bits = (enc & 0x80000000u) ? (enc & 0x7FFFFFFFu) : ~enc;
    float m = __uint_as_float(bits);
    float e = __expf(gate[i] - m);
    gate[i] = e;
    atomicAdd(&segsum[h * NREACT + j], e);
}

__global__ void phase3_kernel(const float* __restrict__ gate, const int* __restrict__ ridx,
                              const float* __restrict__ segsum, float* __restrict__ out)
{
    int n = blockIdx.x * blockDim.x + threadIdx.x;
    if (n >= NELEM) return;
    int j = ridx[n];
    float s = 0.0f;
#pragma unroll
    for (int h = 0; h < NH; ++h)
        s += gate[h * NELEM + n] / (segsum[h * NREACT + j] + 1e-13f);
    out[n] = s * (1.0f / 3.0f);
}

// ---------------- launcher ----------------
extern "C" void kernel_launch(void* const* d_in, const int* in_sizes, int n_in,
                              void* d_out, int out_size, void* d_ws, size_t ws_size,
                              hipStream_t stream)
{
    const float* elem  = (const float*)d_in[0];
    const int*   ridx  = (const int*)  d_in[1];
    const float* embed = (const float*)d_in[2];
    const float* fcW0  = (const float*)d_in[3];
    const float* fcb0  = (const float*)d_in[4];
    const float* fcW1  = (const float*)d_in[5];
    const float* fcb1  = (const float*)d_in[6];
    const float* fcW2  = (const float*)d_in[7];
    const float* fcb2  = (const float*)d_in[8];
    const float* fcW3  = (const float*)d_in[9];
    const float* fcb3  = (const float*)d_in[10];
    const float* fcW4  = (const float*)d_in[11];
    const float* fcb4  = (const float*)d_in[12];
    const float* fcW5  = (const float*)d_in[13];
    const float* fcb5  = (const float*)d_in[14];
    const float* fcW6  = (const float*)d_in[15];
    const float* fcb6  = (const float*)d_in[16];
    const float* resW0 = (const float*)d_in[17];
    const float* resW4 = (const float*)d_in[18];
    const float* resW6 = (const float*)d_in[19];
    const float* outW  = (const float*)d_in[20];
    const float* outb  = (const float*)d_in[21];

    float*        gate   = (float*)d_ws;                  // 600000 f32
    unsigned int* segmax = (unsigned int*)d_ws + 600000;  // 300000 u32
    float*        segsum = (float*)d_ws + 900000;         // 300000 f32
    _Float16*     wbuf   = (_Float16*)((float*)d_ws + 1200000);

    hipMemsetAsync((void*)segmax, 0, sizeof(unsigned int) * 600000, stream);

    // nb = (3*N/64) * (Kpad/32)
    WTab t;
    t.s[0] = { fcW0,  wbuf,           328, 256, 352, 132 };
    t.s[1] = { resW0, wbuf + 270336,  328, 256, 352, 132 };
    t.s[2] = { fcW1,  wbuf + 540672,  256, 256, 256,  96 };
    t.s[3] = { fcW2,  wbuf + 737280,  256, 256, 256,  96 };
    t.s[4] = { fcW3,  wbuf + 933888,  256, 256, 256,  96 };
    t.s[5] = { fcW4,  wbuf + 1130496, 256, 128, 256,  48 };
    t.s[6] = { resW4, wbuf + 1228800, 256, 128, 256,  48 };
    t.s[7] = { fcW5,  wbuf + 1327104, 128, 128, 128,  24 };
    t.s[8] = { fcW6,  wbuf + 1376256, 128,  64, 128,  12 };
    t.s[9] = { resW6, wbuf + 1400832, 128,  64, 128,  12 };
    wconv_all<<<696, 256, 0, stream>>>(t);

    dim3 grid(NELEM / MT, NH);   // head-major: one head's weights stay L2-resident
    mlp_mfma<<<grid, NT, 0, stream>>>(elem, ridx, embed, wbuf,
                                      fcb0, fcb1, fcb2, fcb3, fcb4, fcb5, fcb6,
                                      outW, outb, gate, segmax);

    int tot = NH * NELEM;
    phase2_kernel<<<(tot + 255) / 256, 256, 0, stream>>>(gate, ridx, segmax, segsum);
    phase3_kernel<<<(NELEM + 255) / 256, 256, 0, stream>>>(gate, ridx, segsum, (float*)d_out);
}

// Round 5
// 1419.141 us; speedup vs baseline: 2.4618x; 2.4618x over previous
//
#include <hip/hip_runtime.h>

#define NELEM  200000
#define NREACT 100000
#define EDIM   200
#define RDIM   128
#define F0     328
#define F0PAD  352      // K padded to multiple of 32 for layer 0
#define NH     3
#define MT     64       // rows per block tile
#define NT     256      // 4 waves; ~150 regs/wave pins us at 3 waves/SIMD (R4 lesson)
#define SA     360      // LDS row stride (elems); 720 B rows

typedef _Float16 f16x8 __attribute__((ext_vector_type(8)));
typedef _Float16 f16x4 __attribute__((ext_vector_type(4)));
typedef float    f32x4 __attribute__((ext_vector_type(4)));

// ---------------- fused weight convert + transpose prepass ----------------
// src fp32 [H][K][N] -> dst fp16 [H][N][Kpad], zero-padded for k >= K.
struct WSeg { const float* src; _Float16* dst; int K, N, Kpad, nb; };
struct WTab { WSeg s[10]; };

__global__ void wconv_all(WTab t)
{
    __shared__ float sT[64 * 33];   // [n_local][k_local], stride 33 (conflict-free)
    int b = blockIdx.x;
    for (int i = 0; i < 10; ++i) {
        if (b < t.s[i].nb) {
            const WSeg g = t.s[i];
            const int ntn = 3 * g.N / 64;          // col tiles over H*N
            const int tn = b % ntn, tk = b / ntn;
            const int col = tn * 64;               // global col in [0, 3*N)
            const int h = col / g.N, n0 = col - h * g.N;
            const int k0 = tk * 32;
            const int tid = threadIdx.x;

            // read 32k x 64n tile, coalesced in n
            const int nl = tid & 63;
            for (int kk = tid >> 6; kk < 32; kk += 4) {
                const int k = k0 + kk;
                float v = (k < g.K) ? g.src[((size_t)h * g.K + k) * g.N + n0 + nl] : 0.f;
                sT[nl * 33 + kk] = v;
            }
            __syncthreads();

            // write transposed, coalesced in k
            const int kl = tid & 31;
            for (int nn = tid >> 5; nn < 64; nn += 8)
                g.dst[(size_t)(col + nn) * g.Kpad + k0 + kl] = (_Float16)sT[nn * 33 + kl];
            return;
        }
        b -= t.s[i].nb;
    }
}

// ---------------- sched_group_barrier pinning helpers (T19) ----------------
// Masks: MFMA=0x008, VMEM_READ=0x020, DS_READ=0x100.
// R3 proved these pins are what keeps the prefetch emitted between MFMA
// clusters (without them the scheduler sinks loads to uses; MfmaUtil 14%).
template<int TN>
__device__ __forceinline__ void pin_step_both()   // 4*TN MFMA + TN VMEM + 4 DS
{
    if constexpr (TN == 4) {
#pragma unroll
        for (int g = 0; g < 4; ++g) {
            __builtin_amdgcn_sched_group_barrier(0x008, 2, 0);
            __builtin_amdgcn_sched_group_barrier(0x020, 1, 0);
            __builtin_amdgcn_sched_group_barrier(0x008, 2, 0);
            __builtin_amdgcn_sched_group_barrier(0x100, 1, 0);
        }
    } else if constexpr (TN == 2) {
#pragma unroll
        for (int g = 0; g < 2; ++g) {
            __builtin_amdgcn_sched_group_barrier(0x008, 2, 0);
            __builtin_amdgcn_sched_group_barrier(0x020, 1, 0);
            __builtin_amdgcn_sched_group_barrier(0x008, 2, 0);
            __builtin_amdgcn_sched_group_barrier(0x100, 2, 0);
        }
    } else {   // TN == 1
        __builtin_amdgcn_sched_group_barrier(0x008, 2, 0);
        __builtin_amdgcn_sched_group_barrier(0x020, 1, 0);
        __builtin_amdgcn_sched_group_barrier(0x008, 2, 0);
        __builtin_amdgcn_sched_group_barrier(0x100, 4, 0);
    }
}

template<int TN>
__device__ __forceinline__ void pin_step_aonly()  // 4*TN MFMA + 4 DS
{
    if constexpr (TN == 4) {
#pragma unroll
        for (int g = 0; g < 4; ++g) {
            __builtin_amdgcn_sched_group_barrier(0x008, 4, 0);
            __builtin_amdgcn_sched_group_barrier(0x100, 1, 0);
        }
    } else if constexpr (TN == 2) {
#pragma unroll
        for (int g = 0; g < 4; ++g) {
            __builtin_amdgcn_sched_group_barrier(0x008, 2, 0);
            __builtin_amdgcn_sched_group_barrier(0x100, 1, 0);
        }
    } else {
#pragma unroll
        for (int g = 0; g < 4; ++g) {
            __builtin_amdgcn_sched_group_barrier(0x008, 1, 0);
            __builtin_amdgcn_sched_group_barrier(0x100, 1, 0);
        }
    }
}

template<int N>
__device__ __forceinline__ void pin_step_mfma_only()
{
    __builtin_amdgcn_sched_group_barrier(0x008, N, 0);
}

// ---------------- one GEMM pass: depth-3 B (global/L2) + depth-2 A (LDS) ----------------
// Rotating sets, fully unrolled -> all indices compile-time (no scratch).
// Wait distance for B-loads ~2 step bodies (~200 cyc) ~= L2-hit latency.
// Output layout is SWAPPED mfma(b, a): lane holds 4 consecutive COLS (q*4+i) of one row (r).
template<int TN, int KSTEPS, int KPAD>
__device__ __forceinline__ void gemm_pass(
    const _Float16* __restrict__ buf,
    const _Float16* __restrict__ w,
    f32x4 (&acc)[4][TN], int n0, int r, int q)
{
    const _Float16* aBase = buf + r * SA + q * 8;
    const _Float16* wBase = w + ((size_t)n0 + r) * KPAD + q * 8;

    f16x8 a[2][4], b[3][TN];
#pragma unroll
    for (int s = 0; s < 3; ++s) {
        if (s < KSTEPS) {
#pragma unroll
            for (int nt = 0; nt < TN; ++nt)
                b[s][nt] = *(const f16x8*)(wBase + (size_t)nt * 16 * KPAD + s * 32);
        }
    }
#pragma unroll
    for (int s = 0; s < 2; ++s) {
        if (s < KSTEPS) {
#pragma unroll
            for (int mt = 0; mt < 4; ++mt)
                a[s][mt] = *(const f16x8*)(aBase + mt * 16 * SA + s * 32);
        }
    }

#pragma unroll
    for (int kt = 0; kt < KSTEPS; ++kt) {
        const int bs = kt % 3, as = kt % 2;
#pragma unroll
        for (int nt = 0; nt < TN; ++nt)
#pragma unroll
            for (int mt = 0; mt < 4; ++mt)
                acc[mt][nt] = __builtin_amdgcn_mfma_f32_16x16x32_f16(b[bs][nt], a[as][mt], acc[mt][nt], 0, 0, 0);
        if (kt + 3 < KSTEPS) {
            // refill just-consumed sets: B for kt+3, A for kt+2
#pragma unroll
            for (int nt = 0; nt < TN; ++nt)
                b[bs][nt] = *(const f16x8*)(wBase + (size_t)nt * 16 * KPAD + (kt + 3) * 32);
#pragma unroll
            for (int mt = 0; mt < 4; ++mt)
                a[as][mt] = *(const f16x8*)(aBase + mt * 16 * SA + (kt + 2) * 32);
            pin_step_both<TN>();
        } else if (kt + 2 < KSTEPS) {
#pragma unroll
            for (int mt = 0; mt < 4; ++mt)
                a[as][mt] = *(const f16x8*)(aBase + mt * 16 * SA + (kt + 2) * 32);
            pin_step_aonly<TN>();
        } else {
            pin_step_mfma_only<4 * TN>();
        }
    }
}

// ---------------- identity-residual layer, in-place ----------------
template<int TN, int KSTEPS, int KPAD>
__device__ __forceinline__ void layer_id(
    _Float16* __restrict__ buf,
    const _Float16* __restrict__ wFc,
    const float* __restrict__ bias, int n0, int lane)
{
    const int r = lane & 15, q = lane >> 4;
    f32x4 acc[4][TN];
#pragma unroll
    for (int mt = 0; mt < 4; ++mt)
#pragma unroll
        for (int nt = 0; nt < TN; ++nt) acc[mt][nt] = (f32x4){0.f, 0.f, 0.f, 0.f};

    gemm_pass<TN, KSTEPS, KPAD>(buf, wFc, acc, n0, r, q);

    __syncthreads();   // all waves' reads of buf complete before overwrite

#pragma unroll
    for (int nt = 0; nt < TN; ++nt) {
        const int colb = n0 + nt * 16 + q * 4;
        const f32x4 bv = *(const f32x4*)(bias + colb);
#pragma unroll
        for (int mt = 0; mt < 4; ++mt) {
            _Float16* p = buf + (mt * 16 + r) * SA + colb;
            f16x4 o = *(const f16x4*)p;       // residual (same thread read-then-write)
            f16x4 z;
#pragma unroll
            for (int i = 0; i < 4; ++i)
                z[i] = (_Float16)(fmaxf(acc[mt][nt][i] + bv[i], 0.f) + (float)o[i]);
            *(f16x4*)p = z;
        }
    }
    __syncthreads();   // outputs visible before next layer reads
}

// ---------------- projection-residual layer, in-place ----------------
// pass1: acc = fea*Wfc; relu(acc+bias) in f32; pass2: acc += fea*Wres (MFMA C-in is the add)
template<int TN, int KSTEPS, int KPAD>
__device__ __forceinline__ void layer_proj(
    _Float16* __restrict__ buf,
    const _Float16* __restrict__ wFc, const _Float16* __restrict__ wRes,
    const float* __restrict__ bias, int n0, int lane)
{
    const int r = lane & 15, q = lane >> 4;
    f32x4 acc[4][TN];
#pragma unroll
    for (int mt = 0; mt < 4; ++mt)
#pragma unroll
        for (int nt = 0; nt < TN; ++nt) acc[mt][nt] = (f32x4){0.f, 0.f, 0.f, 0.f};

    gemm_pass<TN, KSTEPS, KPAD>(buf, wFc, acc, n0, r, q);

#pragma unroll
    for (int nt = 0; nt < TN; ++nt) {
        const f32x4 bv = *(const f32x4*)(bias + n0 + nt * 16 + q * 4);
#pragma unroll
        for (int mt = 0; mt < 4; ++mt)
#pragma unroll
            for (int i = 0; i < 4; ++i)
                acc[mt][nt][i] = fmaxf(acc[mt][nt][i] + bv[i], 0.f);
    }

    gemm_pass<TN, KSTEPS, KPAD>(buf, wRes, acc, n0, r, q);   // residual accumulates on top

    __syncthreads();   // all waves' reads of buf complete before overwrite

#pragma unroll
    for (int nt = 0; nt < TN; ++nt) {
        const int colb = n0 + nt * 16 + q * 4;
#pragma unroll
        for (int mt = 0; mt < 4; ++mt) {
            f16x4 z;
#pragma unroll
            for (int i = 0; i < 4; ++i) z[i] = (_Float16)acc[mt][nt][i];
            *(f16x4*)(buf + (mt * 16 + r) * SA + colb) = z;
        }
    }
    __syncthreads();
}

// ---------------- fused MLP kernel ----------------
__global__ __launch_bounds__(NT, 3)
void mlp_mfma(const float* __restrict__ elem, const int* __restrict__ ridx,
              const float* __restrict__ embed,
              const _Float16* __restrict__ wb,
              const float* __restrict__ fcb0, const float* __restrict__ fcb1,
              const float* __restrict__ fcb2, const float* __restrict__ fcb3,
              const float* __restrict__ fcb4, const float* __restrict__ fcb5,
              const float* __restrict__ fcb6,
              const float* __restrict__ outW, const float* __restrict__ outb,
              float* __restrict__ gate, unsigned int* __restrict__ segmax)
{
    __shared__ __align__(16) _Float16 sX[MT * SA];   // 46080 B, in-place all layers
    __shared__ int sidx[MT];

    const int tid = threadIdx.x, lane = tid & 63, wave = tid >> 6;
    const int head = blockIdx.y;                 // head-major dispatch: one head's weights stay L2-resident
    const int row0 = blockIdx.x * MT;

    if (tid < MT) sidx[tid] = ridx[row0 + tid];
    __syncthreads();

    // stage concat(elem, embed[idx]) -> fp16 in sX, float4 loads + 8B LDS writes
    for (int rr = wave; rr < MT; rr += 4) {
        const float* es = elem + (size_t)(row0 + rr) * EDIM;
        const float* ms = embed + (size_t)sidx[rr] * RDIM;
        for (int c = lane; c < F0PAD / 4; c += 64) {          // 88 chunks of 4 floats
            f32x4 v;
            if (c < EDIM / 4)            v = *(const f32x4*)(es + 4 * c);
            else if (c < F0 / 4)         v = *(const f32x4*)(ms + 4 * c - EDIM);
            else                         v = (f32x4){0.f, 0.f, 0.f, 0.f};
            f16x4 hv;
#pragma unroll
            for (int i = 0; i < 4; ++i) hv[i] = (_Float16)v[i];
            *(f16x4*)(sX + rr * SA + 4 * c) = hv;
        }
    }
    __syncthreads();

    const size_t h = head;
    const int n64 = wave * 64, n32 = wave * 32, n16 = wave * 16;

    // weight blob offsets (fp16 elems)
    const _Float16* wt_fc0  = wb;
    const _Float16* wt_res0 = wb + 270336;
    const _Float16* wt_fc1  = wb + 540672;
    const _Float16* wt_fc2  = wb + 737280;
    const _Float16* wt_fc3  = wb + 933888;
    const _Float16* wt_fc4  = wb + 1130496;
    const _Float16* wt_res4 = wb + 1228800;
    const _Float16* wt_fc5  = wb + 1327104;
    const _Float16* wt_fc6  = wb + 1376256;
    const _Float16* wt_res6 = wb + 1400832;

    layer_proj<4, 11, 352>(sX, wt_fc0 + h * 90112, wt_res0 + h * 90112, fcb0 + h * 256, n64, lane);
    layer_id  <4, 8, 256>(sX, wt_fc1 + h * 65536, fcb1 + h * 256, n64, lane);
    layer_id  <4, 8, 256>(sX, wt_fc2 + h * 65536, fcb2 + h * 256, n64, lane);
    layer_id  <4, 8, 256>(sX, wt_fc3 + h * 65536, fcb3 + h * 256, n64, lane);
    layer_proj<2, 8, 256>(sX, wt_fc4 + h * 32768, wt_res4 + h * 32768, fcb4 + h * 128, n32, lane);
    layer_id  <2, 4, 128>(sX, wt_fc5 + h * 16384, fcb5 + h * 128, n32, lane);
    layer_proj<1, 4, 128>(sX, wt_fc6 + h * 8192,  wt_res6 + h * 8192,  fcb6 + h * 64,  n16, lane);

    // gate = h64 . outW + outb ; one thread per row, vectorized LDS reads
    if (tid < MT) {
        const _Float16* hv = sX + tid * SA;
        const float* wv = outW + h * 64;
        float g = outb[head];
#pragma unroll
        for (int j = 0; j < 8; ++j) {
            f16x8 hx = *(const f16x8*)(hv + j * 8);
#pragma unroll
            for (int i = 0; i < 8; ++i) g = fmaf((float)hx[i], wv[j * 8 + i], g);
        }
        gate[head * NELEM + row0 + tid] = g;
        unsigned int bits = __float_as_uint(g);
        unsigned int enc  = (bits & 0x80000000u) ? ~bits : (bits | 0x80000000u);
        atomicMax(&segmax[head * NREACT + sidx[tid]], enc);
    }
}

// ---------------- softmax phases ----------------
__global__ void phase2_kernel(float* __restrict__ gate, const int* __restrict__ ridx,
                              const unsigned int* __restrict__ segmax,
                              float* __restrict__ segsum)
{
    int i = blockIdx.x * blockDim.x + threadIdx.x;
    if (i >= NH * NELEM) return;
    int h = i / NELEM;
    int n = i - h * NELEM;
    int j = ridx[n];
    unsigned int enc  = segmax[h * NREACT + j];
    unsigned int bits = (enc & 0x80000000u) ? (enc & 0x7FFFFFFFu) : ~enc;
    float m = __uint_as_float(bits);
    float e = __expf(gate[i] - m);
    gate[i] = e;
    atomicAdd(&segsum[h * NREACT + j], e);
}

__global__ void phase3_kernel(const float* __restrict__ gate, const int* __restrict__ ridx,
                              const float* __restrict__ segsum, float* __restrict__ out)
{
    int n = blockIdx.x * blockDim.x + threadIdx.x;
    if (n >= NELEM) return;
    int j = ridx[n];
    float s = 0.0f;
#pragma unroll
    for (int h = 0; h < NH; ++h)
        s += gate[h * NELEM + n] / (segsum[h * NREACT + j] + 1e-13f);
    out[n] = s * (1.0f / 3.0f);
}

// ---------------- launcher ----------------
extern "C" void kernel_launch(void* const* d_in, const int* in_sizes, int n_in,
                              void* d_out, int out_size, void* d_ws, size_t ws_size,
                              hipStream_t stream)
{
    const float* elem  = (const float*)d_in[0];
    const int*   ridx  = (const int*)  d_in[1];
    const float* embed = (const float*)d_in[2];
    const float* fcW0  = (const float*)d_in[3];
    const float* fcb0  = (const float*)d_in[4];
    const float* fcW1  = (const float*)d_in[5];
    const float* fcb1  = (const float*)d_in[6];
    const float* fcW2  = (const float*)d_in[7];
    const float* fcb2  = (const float*)d_in[8];
    const float* fcW3  = (const float*)d_in[9];
    const float* fcb3  = (const float*)d_in[10];
    const float* fcW4  = (const float*)d_in[11];
    const float* fcb4  = (const float*)d_in[12];
    const float* fcW5  = (const float*)d_in[13];
    const float* fcb5  = (const float*)d_in[14];
    const float* fcW6  = (const float*)d_in[15];
    const float* fcb6  = (const float*)d_in[16];
    const float* resW0 = (const float*)d_in[17];
    const float* resW4 = (const float*)d_in[18];
    const float* resW6 = (const float*)d_in[19];
    const float* outW  = (const float*)d_in[20];
    const float* outb  = (const float*)d_in[21];

    float*        gate   = (float*)d_ws;                  // 600000 f32
    unsigned int* segmax = (unsigned int*)d_ws + 600000;  // 300000 u32
    float*        segsum = (float*)d_ws + 900000;         // 300000 f32
    _Float16*     wbuf   = (_Float16*)((float*)d_ws + 1200000);

    hipMemsetAsync((void*)segmax, 0, sizeof(unsigned int) * 600000, stream);

    // nb = (3*N/64) * (Kpad/32)
    WTab t;
    t.s[0] = { fcW0,  wbuf,           328, 256, 352, 132 };
    t.s[1] = { resW0, wbuf + 270336,  328, 256, 352, 132 };
    t.s[2] = { fcW1,  wbuf + 540672,  256, 256, 256,  96 };
    t.s[3] = { fcW2,  wbuf + 737280,  256, 256, 256,  96 };
    t.s[4] = { fcW3,  wbuf + 933888,  256, 256, 256,  96 };
    t.s[5] = { fcW4,  wbuf + 1130496, 256, 128, 256,  48 };
    t.s[6] = { resW4, wbuf + 1228800, 256, 128, 256,  48 };
    t.s[7] = { fcW5,  wbuf + 1327104, 128, 128, 128,  24 };
    t.s[8] = { fcW6,  wbuf + 1376256, 128,  64, 128,  12 };
    t.s[9] = { resW6, wbuf + 1400832, 128,  64, 128,  12 };
    wconv_all<<<696, 256, 0, stream>>>(t);

    dim3 grid(NELEM / MT, NH);   // head-major: one head's weights stay L2-resident
    mlp_mfma<<<grid, NT, 0, stream>>>(elem, ridx, embed, wbuf,
                                      fcb0, fcb1, fcb2, fcb3, fcb4, fcb5, fcb6,
                                      outW, outb, gate, segmax);

    int tot = NH * NELEM;
    phase2_kernel<<<(tot + 255) / 256, 256, 0, stream>>>(gate, ridx, segmax, segsum);
    phase3_kernel<<<(NELEM + 255) / 256, 256, 0, stream>>>(gate, ridx, segsum, (float*)d_out);
}

// Round 7
// 1323.103 us; speedup vs baseline: 2.6405x; 1.0726x over previous
//
#include <hip/hip_runtime.h>

#define NELEM  200000
#define NREACT 100000
#define EDIM   200
#define RDIM   128
#define F0     328
#define F0PAD  352      // K padded to multiple of 32 for layer 0
#define NH     3
#define MT     64       // rows per block tile
#define NT     512      // 8 waves, TN=2: ~105 regs/wave -> 4 waves/SIMD at 128-reg cap
#define SA     360      // LDS row stride (elems); 720 B rows

typedef _Float16 f16x8 __attribute__((ext_vector_type(8)));
typedef _Float16 f16x4 __attribute__((ext_vector_type(4)));
typedef float    f32x4 __attribute__((ext_vector_type(4)));

// ---------------- fused weight convert + transpose prepass ----------------
// src fp32 [H][K][N] -> dst fp16 [H][N][Kpad], zero-padded for k >= K.
struct WSeg { const float* src; _Float16* dst; int K, N, Kpad, nb; };
struct WTab { WSeg s[10]; };

__global__ void wconv_all(WTab t)
{
    __shared__ float sT[64 * 33];   // [n_local][k_local], stride 33 (conflict-free)
    int b = blockIdx.x;
    for (int i = 0; i < 10; ++i) {
        if (b < t.s[i].nb) {
            const WSeg g = t.s[i];
            const int ntn = 3 * g.N / 64;          // col tiles over H*N
            const int tn = b % ntn, tk = b / ntn;
            const int col = tn * 64;               // global col in [0, 3*N)
            const int h = col / g.N, n0 = col - h * g.N;
            const int k0 = tk * 32;
            const int tid = threadIdx.x;

            // read 32k x 64n tile, coalesced in n
            const int nl = tid & 63;
            for (int kk = tid >> 6; kk < 32; kk += 4) {
                const int k = k0 + kk;
                float v = (k < g.K) ? g.src[((size_t)h * g.K + k) * g.N + n0 + nl] : 0.f;
                sT[nl * 33 + kk] = v;
            }
            __syncthreads();

            // write transposed, coalesced in k
            const int kl = tid & 31;
            for (int nn = tid >> 5; nn < 64; nn += 8)
                g.dst[(size_t)(col + nn) * g.Kpad + k0 + kl] = (_Float16)sT[nn * 33 + kl];
            return;
        }
        b -= t.s[i].nb;
    }
}

// ---------------- sched_group_barrier pinning helpers (T19) ----------------
// Masks: MFMA=0x008, VMEM_READ=0x020, DS_READ=0x100.
// R3 proved these pins keep the prefetch emitted between MFMA clusters
// (without them the scheduler sinks loads to uses; MfmaUtil 14%).
template<int TN>
__device__ __forceinline__ void pin_step_refill()
{
    if constexpr (TN == 2) {
#pragma unroll
        for (int g = 0; g < 2; ++g) {
            __builtin_amdgcn_sched_group_barrier(0x008, 2, 0);
            __builtin_amdgcn_sched_group_barrier(0x020, 1, 0);
            __builtin_amdgcn_sched_group_barrier(0x008, 2, 0);
            __builtin_amdgcn_sched_group_barrier(0x100, 2, 0);
        }
    } else {   // TN == 1
        __builtin_amdgcn_sched_group_barrier(0x008, 2, 0);
        __builtin_amdgcn_sched_group_barrier(0x020, 1, 0);
        __builtin_amdgcn_sched_group_barrier(0x008, 2, 0);
        __builtin_amdgcn_sched_group_barrier(0x100, 4, 0);
    }
}

template<int N>
__device__ __forceinline__ void pin_step_mfma_only()
{
    __builtin_amdgcn_sched_group_barrier(0x008, N, 0);
}

// ---------------- one GEMM pass, depth-2 modulo pipeline, SGB-pinned ----------------
// Output layout is SWAPPED mfma(b, a): lane holds 4 consecutive COLS (q*4+i) of one row (r).
template<int TN, int KSTEPS, int KPAD>
__device__ __forceinline__ void gemm_pass(
    const _Float16* __restrict__ buf,
    const _Float16* __restrict__ w,
    f32x4 (&acc)[4][TN], int n0, int r, int q)
{
    const _Float16* aBase = buf + r * SA + q * 8;
    const _Float16* wBase = w + ((size_t)n0 + r) * KPAD + q * 8;

    f16x8 a0[4], a1[4], b0[TN], b1[TN];
#pragma unroll
    for (int nt = 0; nt < TN; ++nt) b0[nt] = *(const f16x8*)(wBase + (size_t)nt * 16 * KPAD);
#pragma unroll
    for (int mt = 0; mt < 4; ++mt) a0[mt] = *(const f16x8*)(aBase + mt * 16 * SA);
#pragma unroll
    for (int nt = 0; nt < TN; ++nt) b1[nt] = *(const f16x8*)(wBase + (size_t)nt * 16 * KPAD + 32);
#pragma unroll
    for (int mt = 0; mt < 4; ++mt) a1[mt] = *(const f16x8*)(aBase + mt * 16 * SA + 32);

#pragma unroll
    for (int kt = 0; kt < KSTEPS; kt += 2) {
        // even step: consume set0, refill set0 for kt+2
#pragma unroll
        for (int nt = 0; nt < TN; ++nt)
#pragma unroll
            for (int mt = 0; mt < 4; ++mt)
                acc[mt][nt] = __builtin_amdgcn_mfma_f32_16x16x32_f16(b0[nt], a0[mt], acc[mt][nt], 0, 0, 0);
        if (kt + 2 < KSTEPS) {
#pragma unroll
            for (int nt = 0; nt < TN; ++nt)
                b0[nt] = *(const f16x8*)(wBase + (size_t)nt * 16 * KPAD + (kt + 2) * 32);
#pragma unroll
            for (int mt = 0; mt < 4; ++mt)
                a0[mt] = *(const f16x8*)(aBase + mt * 16 * SA + (kt + 2) * 32);
            pin_step_refill<TN>();
        } else {
            pin_step_mfma_only<4 * TN>();
        }
        // odd step: consume set1, refill set1 for kt+3
        if (kt + 1 < KSTEPS) {
#pragma unroll
            for (int nt = 0; nt < TN; ++nt)
#pragma unroll
                for (int mt = 0; mt < 4; ++mt)
                    acc[mt][nt] = __builtin_amdgcn_mfma_f32_16x16x32_f16(b1[nt], a1[mt], acc[mt][nt], 0, 0, 0);
            if (kt + 3 < KSTEPS) {
#pragma unroll
                for (int nt = 0; nt < TN; ++nt)
                    b1[nt] = *(const f16x8*)(wBase + (size_t)nt * 16 * KPAD + (kt + 3) * 32);
#pragma unroll
                for (int mt = 0; mt < 4; ++mt)
                    a1[mt] = *(const f16x8*)(aBase + mt * 16 * SA + (kt + 3) * 32);
                pin_step_refill<TN>();
            } else {
                pin_step_mfma_only<4 * TN>();
            }
        }
    }
}

// ---------------- identity-residual layer, in-place ----------------
// `active`: wave participates in compute; ALL waves hit both barriers.
template<int TN, int KSTEPS, int KPAD>
__device__ __forceinline__ void layer_id(
    bool active, _Float16* __restrict__ buf,
    const _Float16* __restrict__ wFc,
    const float* __restrict__ bias, int n0, int lane)
{
    const int r = lane & 15, q = lane >> 4;
    f32x4 acc[4][TN];
    if (active) {
#pragma unroll
        for (int mt = 0; mt < 4; ++mt)
#pragma unroll
            for (int nt = 0; nt < TN; ++nt) acc[mt][nt] = (f32x4){0.f, 0.f, 0.f, 0.f};
        gemm_pass<TN, KSTEPS, KPAD>(buf, wFc, acc, n0, r, q);
    }

    __syncthreads();   // all waves' reads of buf complete before overwrite

    if (active) {
#pragma unroll
        for (int nt = 0; nt < TN; ++nt) {
            const int colb = n0 + nt * 16 + q * 4;
            const f32x4 bv = *(const f32x4*)(bias + colb);
#pragma unroll
            for (int mt = 0; mt < 4; ++mt) {
                _Float16* p = buf + (mt * 16 + r) * SA + colb;
                f16x4 o = *(const f16x4*)p;       // residual (same thread read-then-write)
                f16x4 z;
#pragma unroll
                for (int i = 0; i < 4; ++i)
                    z[i] = (_Float16)(fmaxf(acc[mt][nt][i] + bv[i], 0.f) + (float)o[i]);
                *(f16x4*)p = z;
            }
        }
    }
    __syncthreads();   // outputs visible before next layer reads
}

// ---------------- projection-residual layer, in-place ----------------
// pass1: acc = fea*Wfc; relu(acc+bias) in f32; pass2: acc += fea*Wres (MFMA C-in is the add)
template<int TN, int KSTEPS, int KPAD>
__device__ __forceinline__ void layer_proj(
    bool active, _Float16* __restrict__ buf,
    const _Float16* __restrict__ wFc, const _Float16* __restrict__ wRes,
    const float* __restrict__ bias, int n0, int lane)
{
    const int r = lane & 15, q = lane >> 4;
    f32x4 acc[4][TN];
    if (active) {
#pragma unroll
        for (int mt = 0; mt < 4; ++mt)
#pragma unroll
            for (int nt = 0; nt < TN; ++nt) acc[mt][nt] = (f32x4){0.f, 0.f, 0.f, 0.f};

        gemm_pass<TN, KSTEPS, KPAD>(buf, wFc, acc, n0, r, q);

#pragma unroll
        for (int nt = 0; nt < TN; ++nt) {
            const f32x4 bv = *(const f32x4*)(bias + n0 + nt * 16 + q * 4);
#pragma unroll
            for (int mt = 0; mt < 4; ++mt)
#pragma unroll
                for (int i = 0; i < 4; ++i)
                    acc[mt][nt][i] = fmaxf(acc[mt][nt][i] + bv[i], 0.f);
        }

        gemm_pass<TN, KSTEPS, KPAD>(buf, wRes, acc, n0, r, q);   // residual accumulates on top
    }

    __syncthreads();   // all waves' reads of buf complete before overwrite

    if (active) {
#pragma unroll
        for (int nt = 0; nt < TN; ++nt) {
            const int colb = n0 + nt * 16 + q * 4;
#pragma unroll
            for (int mt = 0; mt < 4; ++mt) {
                f16x4 z;
#pragma unroll
                for (int i = 0; i < 4; ++i) z[i] = (_Float16)acc[mt][nt][i];
                *(f16x4*)(buf + (mt * 16 + r) * SA + colb) = z;
            }
        }
    }
    __syncthreads();
}

// ---------------- fused MLP kernel ----------------
// launch_bounds(512, 4): 128-reg cap (TN=2 working set ~105 fits), 4 waves/SIMD.
// R4 lesson: (512,6) forced 85-reg cap -> catastrophic spill. Do NOT raise min-waves.
__global__ __launch_bounds__(NT, 4)
void mlp_mfma(const float* __restrict__ elem, const int* __restrict__ ridx,
              const float* __restrict__ embed,
              const _Float16* __restrict__ wb,
              const float* __restrict__ fcb0, const float* __restrict__ fcb1,
              const float* __restrict__ fcb2, const float* __restrict__ fcb3,
              const float* __restrict__ fcb4, const float* __restrict__ fcb5,
              const float* __restrict__ fcb6,
              const float* __restrict__ outW, const float* __restrict__ outb,
              float* __restrict__ gate, unsigned int* __restrict__ segmax)
{
    __shared__ __align__(16) _Float16 sX[MT * SA];   // 46080 B, in-place all layers
    __shared__ int sidx[MT];

    const int tid = threadIdx.x, lane = tid & 63, wave = tid >> 6;
    const int head = blockIdx.y;                 // head-major dispatch: one head's weights stay L2-resident
    const int row0 = blockIdx.x * MT;

    if (tid < MT) sidx[tid] = ridx[row0 + tid];
    __syncthreads();

    // stage concat(elem, embed[idx]) -> fp16 in sX, float4 loads + 8B LDS writes
    for (int rr = wave; rr < MT; rr += 8) {
        const float* es = elem + (size_t)(row0 + rr) * EDIM;
        const float* ms = embed + (size_t)sidx[rr] * RDIM;
        for (int c = lane; c < F0PAD / 4; c += 64) {          // 88 chunks of 4 floats
            f32x4 v;
            if (c < EDIM / 4)            v = *(const f32x4*)(es + 4 * c);
            else if (c < F0 / 4)         v = *(const f32x4*)(ms + 4 * c - EDIM);
            else                         v = (f32x4){0.f, 0.f, 0.f, 0.f};
            f16x4 hv;
#pragma unroll
            for (int i = 0; i < 4; ++i) hv[i] = (_Float16)v[i];
            *(f16x4*)(sX + rr * SA + 4 * c) = hv;
        }
    }
    __syncthreads();

    const size_t h = head;
    const int n32 = wave * 32, n16 = wave * 16;

    // weight blob offsets (fp16 elems)
    const _Float16* wt_fc0  = wb;
    const _Float16* wt_res0 = wb + 270336;
    const _Float16* wt_fc1  = wb + 540672;
    const _Float16* wt_fc2  = wb + 737280;
    const _Float16* wt_fc3  = wb + 933888;
    const _Float16* wt_fc4  = wb + 1130496;
    const _Float16* wt_res4 = wb + 1228800;
    const _Float16* wt_fc5  = wb + 1327104;
    const _Float16* wt_fc6  = wb + 1376256;
    const _Float16* wt_res6 = wb + 1400832;

    // 8 waves: N=256 layers -> TN=2 (32 cols/wave); N=128 -> TN=1 (16 cols/wave);
    // N=64 -> waves 0-3 only (TN=1), waves 4-7 park at the barriers.
    layer_proj<2, 11, 352>(true, sX, wt_fc0 + h * 90112, wt_res0 + h * 90112, fcb0 + h * 256, n32, lane);
    layer_id  <2, 8, 256>(true, sX, wt_fc1 + h * 65536, fcb1 + h * 256, n32, lane);
    layer_id  <2, 8, 256>(true, sX, wt_fc2 + h * 65536, fcb2 + h * 256, n32, lane);
    layer_id  <2, 8, 256>(true, sX, wt_fc3 + h * 65536, fcb3 + h * 256, n32, lane);
    layer_proj<1, 8, 256>(true, sX, wt_fc4 + h * 32768, wt_res4 + h * 32768, fcb4 + h * 128, n16, lane);
    layer_id  <1, 4, 128>(true, sX, wt_fc5 + h * 16384, fcb5 + h * 128, n16, lane);
    layer_proj<1, 4, 128>(wave < 4, sX, wt_fc6 + h * 8192, wt_res6 + h * 8192, fcb6 + h * 64, n16, lane);

    // gate = h64 . outW + outb ; one thread per row, vectorized LDS reads
    if (tid < MT) {
        const _Float16* hv = sX + tid * SA;
        const float* wv = outW + h * 64;
        float g = outb[head];
#pragma unroll
        for (int j = 0; j < 8; ++j) {
            f16x8 hx = *(const f16x8*)(hv + j * 8);
#pragma unroll
            for (int i = 0; i < 8; ++i) g = fmaf((float)hx[i], wv[j * 8 + i], g);
        }
        gate[head * NELEM + row0 + tid] = g;
        unsigned int bits = __float_as_uint(g);
        unsigned int enc  = (bits & 0x80000000u) ? ~bits : (bits | 0x80000000u);
        atomicMax(&segmax[head * NREACT + sidx[tid]], enc);
    }
}

// ---------------- softmax phases ----------------
__global__ void phase2_kernel(float* __restrict__ gate, const int* __restrict__ ridx,
                              const unsigned int* __restrict__ segmax,
                              float* __restrict__ segsum)
{
    int i = blockIdx.x * blockDim.x + threadIdx.x;
    if (i >= NH * NELEM) return;
    int h = i / NELEM;
    int n = i - h * NELEM;
    int j = ridx[n];
    unsigned int enc  = segmax[h * NREACT + j];
    unsigned int bits = (enc & 0x80000000u) ? (enc & 0x7FFFFFFFu) : ~enc;
    float m = __uint_as_float(bits);
    float e = __expf(gate[i] - m);
    gate[i] = e;
    atomicAdd(&segsum[h * NREACT + j], e);
}

__global__ void phase3_kernel(const float* __restrict__ gate, const int* __restrict__ ridx,
                              const float* __restrict__ segsum, float* __restrict__ out)
{
    int n = blockIdx.x * blockDim.x + threadIdx.x;
    if (n >= NELEM) return;
    int j = ridx[n];
    float s = 0.0f;
#pragma unroll
    for (int h = 0; h < NH; ++h)
        s += gate[h * NELEM + n] / (segsum[h * NREACT + j] + 1e-13f);
    out[n] = s * (1.0f / 3.0f);
}

// ---------------- launcher ----------------
extern "C" void kernel_launch(void* const* d_in, const int* in_sizes, int n_in,
                              void* d_out, int out_size, void* d_ws, size_t ws_size,
                              hipStream_t stream)
{
    const float* elem  = (const float*)d_in[0];
    const int*   ridx  = (const int*)  d_in[1];
    const float* embed = (const float*)d_in[2];
    const float* fcW0  = (const float*)d_in[3];
    const float* fcb0  = (const float*)d_in[4];
    const float* fcW1  = (const float*)d_in[5];
    const float* fcb1  = (const float*)d_in[6];
    const float* fcW2  = (const float*)d_in[7];
    const float* fcb2  = (const float*)d_in[8];
    const float* fcW3  = (const float*)d_in[9];
    const float* fcb3  = (const float*)d_in[10];
    const float* fcW4  = (const float*)d_in[11];
    const float* fcb4  = (const float*)d_in[12];
    const float* fcW5  = (const float*)d_in[13];
    const float* fcb5  = (const float*)d_in[14];
    const float* fcW6  = (const float*)d_in[15];
    const float* fcb6  = (const float*)d_in[16];
    const float* resW0 = (const float*)d_in[17];
    const float* resW4 = (const float*)d_in[18];
    const float* resW6 = (const float*)d_in[19];
    const float* outW  = (const float*)d_in[20];
    const float* outb  = (const float*)d_in[21];

    float*        gate   = (float*)d_ws;                  // 600000 f32
    unsigned int* segmax = (unsigned int*)d_ws + 600000;  // 300000 u32
    float*        segsum = (float*)d_ws + 900000;         // 300000 f32
    _Float16*     wbuf   = (_Float16*)((float*)d_ws + 1200000);

    hipMemsetAsync((void*)segmax, 0, sizeof(unsigned int) * 600000, stream);

    // nb = (3*N/64) * (Kpad/32)
    WTab t;
    t.s[0] = { fcW0,  wbuf,           328, 256, 352, 132 };
    t.s[1] = { resW0, wbuf + 270336,  328, 256, 352, 132 };
    t.s[2] = { fcW1,  wbuf + 540672,  256, 256, 256,  96 };
    t.s[3] = { fcW2,  wbuf + 737280,  256, 256, 256,  96 };
    t.s[4] = { fcW3,  wbuf + 933888,  256, 256, 256,  96 };
    t.s[5] = { fcW4,  wbuf + 1130496, 256, 128, 256,  48 };
    t.s[6] = { resW4, wbuf + 1228800, 256, 128, 256,  48 };
    t.s[7] = { fcW5,  wbuf + 1327104, 128, 128, 128,  24 };
    t.s[8] = { fcW6,  wbuf + 1376256, 128,  64, 128,  12 };
    t.s[9] = { resW6, wbuf + 1400832, 128,  64, 128,  12 };
    wconv_all<<<696, 256, 0, stream>>>(t);

    dim3 grid(NELEM / MT, NH);   // head-major: one head's weights stay L2-resident
    mlp_mfma<<<grid, NT, 0, stream>>>(elem, ridx, embed, wbuf,
                                      fcb0, fcb1, fcb2, fcb3, fcb4, fcb5, fcb6,
                                      outW, outb, gate, segmax);

    int tot = NH * NELEM;
    phase2_kernel<<<(tot + 255) / 256, 256, 0, stream>>>(gate, ridx, segmax, segsum);
    phase3_kernel<<<(NELEM + 255) / 256, 256, 0, stream>>>(gate, ridx, segsum, (float*)d_out);
}